// Round 14
// baseline (37.069 us; speedup 1.0000x reference)
//
#include <hip/hip_runtime.h>
#include <hip/hip_bf16.h>
#include <math.h>

// Gaussian upsampling, round 14: single-barrier merged phases (MFMA || VALU || stores).
//   K0 transpose_enc_bf16 : enc -> pre-permuted encT (validated)
//   K0b pe_table          : pe[T,D] f32 (validated R8)
//   K1 gauss_fused5       : grid 256 (1/CU), 512 thr (8 waves). Block = (b, 256
//                           t-rows = 4 tiles of 64), wave owns d-span wid*32.
//     Per phase p (ONE raw barrier each):
//       epilogue(p-1) [stg-transpose + PE-table + f32x4 stores, issued first]
//       winv(p) | kloop(p) on A[p&1], B in regs | exp(p+1) -> A[(p+1)&1]
//     Double-buffered: s_A, s_part, s_winv; two static acc sets (accA/accB).

typedef short  bf16x8 __attribute__((ext_vector_type(8)));
typedef float  f32x4  __attribute__((ext_vector_type(4)));
typedef int    i32x4  __attribute__((ext_vector_type(4)));
typedef unsigned short u16x8 __attribute__((ext_vector_type(8)));

#define S_FIX 256
#define D_FIX 256
#define BM    64      // t-rows per tile
#define NTILE 4       // tiles per block (256 rows)
#define STG   40      // epilogue staging stride (floats)

static __device__ __forceinline__ unsigned short f2bf(float f) {
    union { float f; unsigned u; } v; v.f = f;
    unsigned r = v.u + 0x7FFFu + ((v.u >> 16) & 1u);   // RNE
    return (unsigned short)(r >> 16);
}

static __device__ __forceinline__ unsigned pack_bf2(float lo, float hi) {
    float2 v; v.x = lo; v.y = hi;
    union { __hip_bfloat162 h; unsigned u; } c;
    c.h = __float22bfloat162_rn(v);
    return c.u;   // low16 = bf16(lo), high16 = bf16(hi)
}

// ---------------- K0: enc -> encT (pre-permuted; validated) ----------------
__global__ __launch_bounds__(256) void transpose_enc_bf16(
    const float* __restrict__ enc, unsigned short* __restrict__ encT)
{
    const int g  = blockIdx.x * 256 + threadIdx.x;
    const int d  = g & 255;
    const int sc = (g >> 8) & 31;     // 8-s chunk
    const int b  = g >> 13;
    const int s0 = sc * 8;
    const float* p = enc + ((size_t)b << 16) + (size_t)s0 * D_FIX + d;
    u16x8 v;
    #pragma unroll
    for (int j = 0; j < 8; ++j) v[j] = f2bf(p[(size_t)j * D_FIX]);
    const int dh = d >> 7, dl = d & 127;
    const size_t off = ((size_t)b << 17) + ((size_t)dh << 16)
                     + (size_t)dl * 512 + (unsigned)((16 * sc) ^ ((dl & 15) << 4));
    *(u16x8*)((char*)encT + off) = v;
}

// ---------------- K0b: pe[T,D] table (validated R8) ----------------
__global__ __launch_bounds__(256) void pe_table(float* __restrict__ pe)
{
    const int idx = blockIdx.x * 256 + threadIdx.x;   // T*64 threads
    const int q   = idx & 63;
    const int t   = idx >> 6;
    const float kf = -logf(10000.0f) / (float)D_FIX;
    const float f0 = __expf(kf * (float)(4 * q));
    const float f2 = __expf(kf * (float)(4 * q + 2));
    float s0, c0, s2, c2;
    __sincosf((float)t * f0, &s0, &c0);
    __sincosf((float)t * f2, &s2, &c2);
    f32x4 v; v[0] = s0; v[1] = c0; v[2] = s2; v[3] = c2;
    *(f32x4*)(pe + (size_t)t * D_FIX + 4 * q) = v;
}

// ---------------- K1: fused main, merged phases ----------------
__global__ __launch_bounds__(512) void gauss_fused5(
    const float* __restrict__ dur,            // (B,S)
    const float* __restrict__ rng,            // (B,S,1)
    const unsigned short* __restrict__ encT,  // permuted (B,2,128,256)
    const float* __restrict__ pe,             // (T,D)
    float* __restrict__ out,                  // (B,T,D)
    int T)
{
    __shared__ __align__(16) short s_A[2][BM * S_FIX];   // 64 KB
    __shared__ __align__(16) float s_stg[8][16 * STG];   // 20 KB
    __shared__ float s_c[S_FIX];
    __shared__ float s_nir[S_FIX];
    __shared__ float s_part[2][8][BM];
    __shared__ float s_winv[2][BM];

    const int tid  = threadIdx.x;
    const int lane = tid & 63;
    const int wid  = tid >> 6;       // 0..7 -> d-span wid*32
    const int l15  = lane & 15;
    const int lg   = lane >> 4;
    const int nseg = T / (BM * NTILE);            // 8
    const int b    = blockIdx.x / nseg;
    const int tb   = (blockIdx.x % nseg) * (BM * NTILE);
    const int dhw  = wid >> 2;
    const int wdl  = wid & 3;

    // ---- B fragments from global (pre-permuted layout), ONCE ----
    bf16x8 breg0[8], breg1[8];
    {
        const char* gB = (const char*)encT + ((size_t)b << 17) + ((size_t)dhw << 16);
        const char* r0 = gB + (size_t)(wdl * 32 + l15) * 512;
        const char* r1 = r0 + 16 * 512;
        #pragma unroll
        for (int ks = 0; ks < 8; ++ks) {
            const int koff = (2 * (ks * 32 + lg * 8)) ^ (l15 << 4);
            breg0[ks] = *(const bf16x8*)(r0 + koff);
            breg1[ks] = *(const bf16x8*)(r1 + koff);
        }
    }

    // ---- per-wave scan (8 waves redundant; identical-value race benign) ----
    {
        f32x4 dv = *(const f32x4*)(dur + b * S_FIX + 4 * lane);
        f32x4 rg = *(const f32x4*)(rng + b * S_FIX + 4 * lane);
        float q0 = dv[0];
        float q1 = q0 + dv[1];
        float q2 = q1 + dv[2];
        float q3 = q2 + dv[3];
        float tot = q3;
        #pragma unroll
        for (int off = 1; off < 64; off <<= 1) {
            float n = __shfl_up(tot, off, 64);
            if (lane >= off) tot += n;
        }
        float excl = __shfl_up(tot, 1, 64);
        if (lane == 0) excl = 0.0f;
        f32x4 c4, n4;
        c4[0] = excl + q0 - 0.5f * dv[0];
        c4[1] = excl + q1 - 0.5f * dv[1];
        c4[2] = excl + q2 - 0.5f * dv[2];
        c4[3] = excl + q3 - 0.5f * dv[3];
        #pragma unroll
        for (int i = 0; i < 4; ++i) n4[i] = -1.0f / (rg[i] * rg[i]);
        *(f32x4*)(s_c   + 4 * lane) = c4;
        *(f32x4*)(s_nir + 4 * lane) = n4;
    }
    asm volatile("s_waitcnt lgkmcnt(0)" ::: "memory");

    const int q8 = lane & 7;
    const int dq = wid * 32 + 4 * q8;                  // absolute d (mult of 4)

    // ---- helpers ----
    auto exp_tile = [&](int t0e, int buf) {
        const int r  = tid & 63;
        const int kc = tid >> 6;
        const float tt = (float)(t0e + r);
        const int swz = (r & 15) << 4;
        char* arow = (char*)s_A[buf] + (size_t)r * 512;
        float ps = 0.0f;
        #pragma unroll
        for (int c8 = 0; c8 < 4; ++c8) {
            i32x4 pk;
            #pragma unroll
            for (int jj = 0; jj < 4; ++jj) {
                const int k = kc * 32 + c8 * 8 + 2 * jj;
                float2 cc = *(const float2*)(s_c + k);
                float2 nn = *(const float2*)(s_nir + k);
                float e0 = tt - cc.x, e1 = tt - cc.y;
                unsigned p = pack_bf2(__expf(nn.x * e0 * e0), __expf(nn.y * e1 * e1));
                pk[jj] = (int)p;
                ps += __uint_as_float(p << 16) + __uint_as_float(p & 0xFFFF0000u);
            }
            *(i32x4*)(arow + ((kc * 64 + c8 * 16) ^ swz)) = pk;
        }
        s_part[buf][kc][r] = ps;
    };

    auto do_winv = [&](int buf) {
        if (tid < BM) {
            float w2 = 1e-20f;
            #pragma unroll
            for (int kc = 0; kc < 8; ++kc) w2 += s_part[buf][kc][tid];
            s_winv[buf][tid] = 1.0f / w2;
        }
    };

    auto do_kloop = [&](int buf, f32x4 (&acc)[4][2]) {
        #pragma unroll
        for (int m = 0; m < 4; ++m)
            #pragma unroll
            for (int n = 0; n < 2; ++n) acc[m][n] = (f32x4){0.f, 0.f, 0.f, 0.f};
        const char* aB = (const char*)s_A[buf] + (size_t)l15 * 512;
        #pragma unroll
        for (int ks = 0; ks < 8; ++ks) {
            const int koff = (2 * (ks * 32 + lg * 8)) ^ (l15 << 4);
            bf16x8 a0 = *(const bf16x8*)(aB + koff);
            bf16x8 a1 = *(const bf16x8*)(aB + 8192  + koff);
            bf16x8 a2 = *(const bf16x8*)(aB + 16384 + koff);
            bf16x8 a3 = *(const bf16x8*)(aB + 24576 + koff);
            acc[0][0] = __builtin_amdgcn_mfma_f32_16x16x32_bf16(a0, breg0[ks], acc[0][0], 0, 0, 0);
            acc[0][1] = __builtin_amdgcn_mfma_f32_16x16x32_bf16(a0, breg1[ks], acc[0][1], 0, 0, 0);
            acc[1][0] = __builtin_amdgcn_mfma_f32_16x16x32_bf16(a1, breg0[ks], acc[1][0], 0, 0, 0);
            acc[1][1] = __builtin_amdgcn_mfma_f32_16x16x32_bf16(a1, breg1[ks], acc[1][1], 0, 0, 0);
            acc[2][0] = __builtin_amdgcn_mfma_f32_16x16x32_bf16(a2, breg0[ks], acc[2][0], 0, 0, 0);
            acc[2][1] = __builtin_amdgcn_mfma_f32_16x16x32_bf16(a2, breg1[ks], acc[2][1], 0, 0, 0);
            acc[3][0] = __builtin_amdgcn_mfma_f32_16x16x32_bf16(a3, breg0[ks], acc[3][0], 0, 0, 0);
            acc[3][1] = __builtin_amdgcn_mfma_f32_16x16x32_bf16(a3, breg1[ks], acc[3][1], 0, 0, 0);
        }
    };

    auto do_epi = [&](int t0r, int buf, f32x4 (&acc)[4][2]) {
        float* stg = s_stg[wid];
        #pragma unroll
        for (int m = 0; m < 4; ++m) {
            asm volatile("s_waitcnt lgkmcnt(0)" ::: "memory");  // WAR on stg
            #pragma unroll
            for (int n = 0; n < 2; ++n)
                #pragma unroll
                for (int r = 0; r < 4; ++r)
                    stg[(lg * 4 + r) * STG + n * 16 + l15] = acc[m][n][r];
            asm volatile("s_waitcnt lgkmcnt(0)" ::: "memory");
            const int rl = lane >> 3;
            #pragma unroll
            for (int h = 0; h < 2; ++h) {
                const int rr = rl + 8 * h;                 // 0..15
                const int tr = m * 16 + rr;                // row in tile 0..63
                f32x4 v = *(const f32x4*)(stg + rr * STG + 4 * q8);
                const float iv = s_winv[buf][tr];
                f32x4 p = *(const f32x4*)(pe + (size_t)(t0r + tr) * D_FIX + dq);
                v[0] = v[0] * iv + p[0];
                v[1] = v[1] * iv + p[1];
                v[2] = v[2] * iv + p[2];
                v[3] = v[3] * iv + p[3];
                *(f32x4*)(out + ((size_t)b * T + t0r + tr) * D_FIX + dq) = v;
            }
        }
    };

    #define PHASE_BAR()  do {                                   \
        asm volatile("s_waitcnt lgkmcnt(0)" ::: "memory");      \
        __builtin_amdgcn_s_barrier();                           \
        asm volatile("" ::: "memory");                          \
    } while (0)

    // ---- prologue: exp(0) -> A[0] ----
    exp_tile(tb, 0);
    PHASE_BAR();

    f32x4 accA[4][2], accB[4][2];

    // phase 0: winv(0) | kloop(0)->accA | exp(1)->A[1]
    do_winv(0);
    do_kloop(0, accA);
    exp_tile(tb + 1 * BM, 1);
    PHASE_BAR();

    // phase 1: epi(0,accA) | winv(1) | kloop(1)->accB | exp(2)->A[0]
    do_epi(tb + 0 * BM, 0, accA);
    do_winv(1);
    do_kloop(1, accB);
    exp_tile(tb + 2 * BM, 0);
    PHASE_BAR();

    // phase 2: epi(1,accB) | winv(0) | kloop(0)->accA | exp(3)->A[1]
    do_epi(tb + 1 * BM, 1, accB);
    do_winv(0);
    do_kloop(0, accA);
    exp_tile(tb + 3 * BM, 1);
    PHASE_BAR();

    // phase 3: epi(2,accA) | winv(1) | kloop(1)->accB
    do_epi(tb + 2 * BM, 0, accA);
    do_winv(1);
    do_kloop(1, accB);
    PHASE_BAR();

    // final epilogue
    do_epi(tb + 3 * BM, 1, accB);

    #undef PHASE_BAR
}

// ---------------- fallback (round-1 f32 kernel) ----------------
#define FBM 32
#define BLOCK 256
__global__ __launch_bounds__(BLOCK) void gauss_up_f32(
    const float* __restrict__ enc, const float* __restrict__ dur,
    const float* __restrict__ rng, float* __restrict__ out,
    int T, int D, int ntiles)
{
    __shared__ float s_w[FBM][S_FIX];
    __shared__ float s_c[S_FIX];
    __shared__ float s_ir2[S_FIX];
    __shared__ float s_scan[S_FIX];
    __shared__ float s_part[8][FBM];
    __shared__ float s_winv[FBM];

    const int tid = threadIdx.x;
    const int b   = blockIdx.x / ntiles;
    const int t0  = (blockIdx.x % ntiles) * FBM;

    float dv = dur[b * S_FIX + tid];
    s_scan[tid] = dv;
    __syncthreads();
    #pragma unroll
    for (int off = 1; off < S_FIX; off <<= 1) {
        float cur = s_scan[tid];
        float add = (tid >= off) ? s_scan[tid - off] : 0.0f;
        __syncthreads();
        s_scan[tid] = cur + add;
        __syncthreads();
    }
    {
        float e = s_scan[tid];
        float c = e - 0.5f * dv;
        float r = rng[b * S_FIX + tid];
        s_c[tid] = c; s_ir2[tid] = 1.0f / (r * r);
    }
    __syncthreads();
    {
        float cc = s_c[tid], ir = s_ir2[tid];
        #pragma unroll 4
        for (int tl = 0; tl < FBM; ++tl) {
            float tt = (float)(t0 + tl);
            float df = tt - cc;
            s_w[tl][tid] = __expf(-ir * df * df);
        }
    }
    __syncthreads();
    {
        const int t = tid & 31, ch = tid >> 5;
        float ps = 0.0f;
        #pragma unroll 8
        for (int j = 0; j < 32; ++j) ps += s_w[t][ch * 32 + ((j + t) & 31)];
        s_part[ch][t] = ps;
    }
    __syncthreads();
    if (tid < FBM) {
        float w2 = s_part[0][tid] + s_part[1][tid] + s_part[2][tid] + s_part[3][tid]
                 + s_part[4][tid] + s_part[5][tid] + s_part[6][tid] + s_part[7][tid] + 1e-20f;
        s_winv[tid] = 1.0f / w2;
    }
    __syncthreads();

    const int dq = tid & 63, tg = tid >> 6;
    float4 acc[8];
    #pragma unroll
    for (int i = 0; i < 8; ++i) acc[i] = make_float4(0.f, 0.f, 0.f, 0.f);
    const float* encb = enc + (size_t)b * S_FIX * D + (size_t)dq * 4;
    #pragma unroll 4
    for (int s = 0; s < S_FIX; ++s) {
        float4 ev = *(const float4*)(encb + (size_t)s * D);
        #pragma unroll
        for (int i = 0; i < 8; ++i) {
            float wv = s_w[tg * 8 + i][s];
            acc[i].x = fmaf(wv, ev.x, acc[i].x);
            acc[i].y = fmaf(wv, ev.y, acc[i].y);
            acc[i].z = fmaf(wv, ev.z, acc[i].z);
            acc[i].w = fmaf(wv, ev.w, acc[i].w);
        }
    }
    const float kf = -logf(10000.0f) / (float)D;
    const int d0 = dq * 4;
    const float f0 = __expf(kf * (float)(d0));
    const float f2 = __expf(kf * (float)(d0 + 2));
    float* outb = out + (size_t)b * T * D + (size_t)t0 * D + d0;
    #pragma unroll
    for (int i = 0; i < 8; ++i) {
        const int tl = tg * 8 + i;
        const float inv = s_winv[tl];
        const float tt = (float)(t0 + tl);
        const float a0 = tt * f0, a2 = tt * f2;
        float4 o;
        o.x = acc[i].x * inv + __sinf(a0);
        o.y = acc[i].y * inv + __cosf(a0);
        o.z = acc[i].z * inv + __sinf(a2);
        o.w = acc[i].w * inv + __cosf(a2);
        *(float4*)(outb + (size_t)tl * D) = o;
    }
}

extern "C" void kernel_launch(void* const* d_in, const int* in_sizes, int n_in,
                              void* d_out, int out_size, void* d_ws, size_t ws_size,
                              hipStream_t stream) {
    const float* enc = (const float*)d_in[0];
    const float* dur = (const float*)d_in[1];
    const float* rng = (const float*)d_in[2];
    float* out = (float*)d_out;

    const int S  = S_FIX;
    const int BS = in_sizes[1];
    const int B  = BS / S;
    const int D  = in_sizes[0] / BS;
    const int T  = out_size / (B * D);

    const size_t sz_encT = (size_t)B * D * S * sizeof(unsigned short);  // 4 MB
    const size_t sz_pe   = (size_t)T * D * sizeof(float);               // 2 MB
    const size_t need    = sz_encT + sz_pe;

    if (D == D_FIX && S == S_FIX && (T % (BM * NTILE)) == 0 && ws_size >= need) {
        unsigned short* encT = (unsigned short*)d_ws;
        float* pe = (float*)((char*)d_ws + sz_encT);
        hipLaunchKernelGGL(transpose_enc_bf16, dim3(B * (S / 8) * D / 256), dim3(256),
                           0, stream, enc, encT);
        hipLaunchKernelGGL(pe_table, dim3(T * 64 / 256), dim3(256), 0, stream, pe);
        const int grid = B * (T / (BM * NTILE));   // 32*8 = 256
        hipLaunchKernelGGL(gauss_fused5, dim3(grid), dim3(512), 0, stream,
                           dur, rng, encT, pe, out, T);
    } else {
        const int ntiles = T / FBM;
        hipLaunchKernelGGL(gauss_up_f32, dim3(B * ntiles), dim3(BLOCK), 0, stream,
                           enc, dur, rng, out, T, D, ntiles);
    }
}

// Round 15
// 35.770 us; speedup vs baseline: 1.0363x; 1.0363x over previous
//
#include <hip/hip_runtime.h>
#include <hip/hip_bf16.h>
#include <math.h>

// Gaussian upsampling, round 15: R13 + Gaussian window sparsity (bit-exact skip).
//   K0 transpose_enc_bf16 : enc -> pre-permuted encT (validated)
//   K0b pe_table          : pe[T,D] f32 (validated R8)
//   K1 gauss_fused6       : R13 skeleton (grid 256 = 1/CU, 512 thr, full-D,
//                           B-in-regs, 2 bars/tile) plus:
//     - per-tile token window [klo,khi): token k active iff
//       mindist(c_k,[t0,t0+63])^2 * ir2_k <= 110  (exp(-110) == 0.0f in f32 ->
//       skipping is EXACT vs the f32 reference, not an approximation)
//     - exp phase: inactive 32-token chunks write only s_part=0 (s_A unread there)
//     - kloop: static 8-ks unroll, wave-uniform guard ks in [kslo,kshi)
//     - epilogue: PE table loads instead of 16 sincos/tile

typedef short  bf16x8 __attribute__((ext_vector_type(8)));
typedef float  f32x4  __attribute__((ext_vector_type(4)));
typedef int    i32x4  __attribute__((ext_vector_type(4)));
typedef unsigned short u16x8 __attribute__((ext_vector_type(8)));

#define S_FIX 256
#define D_FIX 256
#define BM    64      // t-rows per tile
#define NTILE 4       // tiles per block (256 rows)
#define STG   40      // epilogue staging stride (floats)

static __device__ __forceinline__ unsigned short f2bf(float f) {
    union { float f; unsigned u; } v; v.f = f;
    unsigned r = v.u + 0x7FFFu + ((v.u >> 16) & 1u);   // RNE
    return (unsigned short)(r >> 16);
}

static __device__ __forceinline__ unsigned pack_bf2(float lo, float hi) {
    float2 v; v.x = lo; v.y = hi;
    union { __hip_bfloat162 h; unsigned u; } c;
    c.h = __float22bfloat162_rn(v);
    return c.u;   // low16 = bf16(lo), high16 = bf16(hi)
}

// ---------------- K0: enc -> encT (pre-permuted; validated) ----------------
__global__ __launch_bounds__(256) void transpose_enc_bf16(
    const float* __restrict__ enc, unsigned short* __restrict__ encT)
{
    const int g  = blockIdx.x * 256 + threadIdx.x;
    const int d  = g & 255;
    const int sc = (g >> 8) & 31;     // 8-s chunk
    const int b  = g >> 13;
    const int s0 = sc * 8;
    const float* p = enc + ((size_t)b << 16) + (size_t)s0 * D_FIX + d;
    u16x8 v;
    #pragma unroll
    for (int j = 0; j < 8; ++j) v[j] = f2bf(p[(size_t)j * D_FIX]);
    const int dh = d >> 7, dl = d & 127;
    const size_t off = ((size_t)b << 17) + ((size_t)dh << 16)
                     + (size_t)dl * 512 + (unsigned)((16 * sc) ^ ((dl & 15) << 4));
    *(u16x8*)((char*)encT + off) = v;
}

// ---------------- K0b: pe[T,D] table (validated R8) ----------------
__global__ __launch_bounds__(256) void pe_table(float* __restrict__ pe)
{
    const int idx = blockIdx.x * 256 + threadIdx.x;   // T*64 threads
    const int q   = idx & 63;
    const int t   = idx >> 6;
    const float kf = -logf(10000.0f) / (float)D_FIX;
    const float f0 = __expf(kf * (float)(4 * q));
    const float f2 = __expf(kf * (float)(4 * q + 2));
    float s0, c0, s2, c2;
    __sincosf((float)t * f0, &s0, &c0);
    __sincosf((float)t * f2, &s2, &c2);
    f32x4 v; v[0] = s0; v[1] = c0; v[2] = s2; v[3] = c2;
    *(f32x4*)(pe + (size_t)t * D_FIX + 4 * q) = v;
}

// ---------------- K1: fused main (full-D, windowed) ----------------
__global__ __launch_bounds__(512) void gauss_fused6(
    const float* __restrict__ dur,            // (B,S)
    const float* __restrict__ rng,            // (B,S,1)
    const unsigned short* __restrict__ encT,  // permuted (B,2,128,256)
    const float* __restrict__ pe,             // (T,D)
    float* __restrict__ out,                  // (B,T,D)
    int T)
{
    __shared__ __align__(16) short s_A[BM * S_FIX];      // 32 KB
    __shared__ __align__(16) float s_stg[8][16 * STG];   // 20 KB
    __shared__ float s_c[S_FIX];
    __shared__ float s_nir[S_FIX];
    __shared__ float s_part[8][BM];
    __shared__ float s_winv[BM];

    const int tid  = threadIdx.x;
    const int lane = tid & 63;
    const int wid  = tid >> 6;       // 0..7 -> d-span wid*32
    const int l15  = lane & 15;
    const int lg   = lane >> 4;
    const int nseg = T / (BM * NTILE);            // 8
    const int b    = blockIdx.x / nseg;
    const int tb   = (blockIdx.x % nseg) * (BM * NTILE);
    const int dhw  = wid >> 2;
    const int wdl  = wid & 3;

    // ---- B fragments from global (pre-permuted layout), ONCE ----
    bf16x8 breg0[8], breg1[8];
    {
        const char* gB = (const char*)encT + ((size_t)b << 17) + ((size_t)dhw << 16);
        const char* r0 = gB + (size_t)(wdl * 32 + l15) * 512;
        const char* r1 = r0 + 16 * 512;
        #pragma unroll
        for (int ks = 0; ks < 8; ++ks) {
            const int koff = (2 * (ks * 32 + lg * 8)) ^ (l15 << 4);
            breg0[ks] = *(const bf16x8*)(r0 + koff);
            breg1[ks] = *(const bf16x8*)(r1 + koff);
        }
    }

    // ---- per-wave scan (8 waves redundant; identical-value race benign) ----
    {
        f32x4 dv = *(const f32x4*)(dur + b * S_FIX + 4 * lane);
        f32x4 rg = *(const f32x4*)(rng + b * S_FIX + 4 * lane);
        float q0 = dv[0];
        float q1 = q0 + dv[1];
        float q2 = q1 + dv[2];
        float q3 = q2 + dv[3];
        float tot = q3;
        #pragma unroll
        for (int off = 1; off < 64; off <<= 1) {
            float n = __shfl_up(tot, off, 64);
            if (lane >= off) tot += n;
        }
        float excl = __shfl_up(tot, 1, 64);
        if (lane == 0) excl = 0.0f;
        f32x4 c4, n4;
        c4[0] = excl + q0 - 0.5f * dv[0];
        c4[1] = excl + q1 - 0.5f * dv[1];
        c4[2] = excl + q2 - 0.5f * dv[2];
        c4[3] = excl + q3 - 0.5f * dv[3];
        #pragma unroll
        for (int i = 0; i < 4; ++i) n4[i] = -1.0f / (rg[i] * rg[i]);
        *(f32x4*)(s_c   + 4 * lane) = c4;
        *(f32x4*)(s_nir + 4 * lane) = n4;
    }
    asm volatile("s_waitcnt lgkmcnt(0)" ::: "memory");   // own writes visible

    const int q8 = lane & 7;
    const int dq = wid * 32 + 4 * q8;                  // absolute d (mult of 4)

    // ---- per-tile token window: k active iff mindist^2 * ir2 <= 110
    //      (exp(-110) == 0.0f exactly in f32 -> skip is bit-exact) ----
    auto tile_window = [&](int t0e, int& klo, int& khi) {
        f32x4 c4 = *(const f32x4*)(s_c   + 4 * lane);
        f32x4 n4 = *(const f32x4*)(s_nir + 4 * lane);   // -1/r^2
        bool any = false;
        #pragma unroll
        for (int j = 0; j < 4; ++j) {
            float lo = (float)t0e - c4[j];
            float hi = c4[j] - (float)(t0e + BM - 1);
            float dd = fmaxf(0.0f, fmaxf(lo, hi));
            any = any || (dd * dd * (-n4[j]) <= 110.0f);
        }
        unsigned long long m = __ballot(any ? 1 : 0);
        if (m == 0ULL) { klo = 0; khi = 0; return; }
        klo = 4 * __builtin_ctzll(m);
        khi = 4 * (63 - __builtin_clzll(m)) + 4;
    };

    // ---- exp-tile generator (b128 writes; windowed) ----
    auto exp_tile = [&](int t0e) {
        int klo, khi;
        tile_window(t0e, klo, khi);
        const int r  = tid & 63;
        const int kc = tid >> 6;
        const bool active = (kc * 32 + 32 > klo) && (kc * 32 < khi);
        float ps = 0.0f;
        if (active) {
            const float tt = (float)(t0e + r);
            const int swz = (r & 15) << 4;
            char* arow = (char*)s_A + (size_t)r * 512;
            #pragma unroll
            for (int c8 = 0; c8 < 4; ++c8) {
                i32x4 pk;
                #pragma unroll
                for (int jj = 0; jj < 4; ++jj) {
                    const int k = kc * 32 + c8 * 8 + 2 * jj;
                    float2 cc = *(const float2*)(s_c + k);
                    float2 nn = *(const float2*)(s_nir + k);
                    float e0 = tt - cc.x, e1 = tt - cc.y;
                    unsigned p = pack_bf2(__expf(nn.x * e0 * e0), __expf(nn.y * e1 * e1));
                    pk[jj] = (int)p;
                    ps += __uint_as_float(p << 16) + __uint_as_float(p & 0xFFFF0000u);
                }
                *(i32x4*)(arow + ((kc * 64 + c8 * 16) ^ swz)) = pk;
            }
        }
        s_part[kc][r] = ps;
    };

    // ---- prologue: exp(0) ----
    exp_tile(tb);
    asm volatile("s_waitcnt lgkmcnt(0)" ::: "memory");
    __builtin_amdgcn_s_barrier();
    asm volatile("" ::: "memory");

    f32x4 acc[4][2];

    for (int tile = 0; tile < NTILE; ++tile) {
        const int t0 = tb + tile * BM;

        // winv(tile)
        if (tid < BM) {
            float w2 = 1e-20f;
            #pragma unroll
            for (int kc = 0; kc < 8; ++kc) w2 += s_part[kc][tid];
            s_winv[tid] = 1.0f / w2;
        }

        // kloop: windowed static unroll; A from LDS, B from registers
        #pragma unroll
        for (int m = 0; m < 4; ++m)
            #pragma unroll
            for (int n = 0; n < 2; ++n) acc[m][n] = (f32x4){0.f, 0.f, 0.f, 0.f};
        {
            int klo, khi;
            tile_window(t0, klo, khi);
            const int kslo = klo >> 5;
            const int kshi = (khi + 31) >> 5;
            const char* aB = (const char*)s_A + (size_t)l15 * 512;
            #pragma unroll
            for (int ks = 0; ks < 8; ++ks) {
                if (ks >= kslo && ks < kshi) {     // wave-uniform guard
                    const int koff = (2 * (ks * 32 + lg * 8)) ^ (l15 << 4);
                    bf16x8 a0 = *(const bf16x8*)(aB + koff);
                    bf16x8 a1 = *(const bf16x8*)(aB + 8192  + koff);
                    bf16x8 a2 = *(const bf16x8*)(aB + 16384 + koff);
                    bf16x8 a3 = *(const bf16x8*)(aB + 24576 + koff);
                    acc[0][0] = __builtin_amdgcn_mfma_f32_16x16x32_bf16(a0, breg0[ks], acc[0][0], 0, 0, 0);
                    acc[0][1] = __builtin_amdgcn_mfma_f32_16x16x32_bf16(a0, breg1[ks], acc[0][1], 0, 0, 0);
                    acc[1][0] = __builtin_amdgcn_mfma_f32_16x16x32_bf16(a1, breg0[ks], acc[1][0], 0, 0, 0);
                    acc[1][1] = __builtin_amdgcn_mfma_f32_16x16x32_bf16(a1, breg1[ks], acc[1][1], 0, 0, 0);
                    acc[2][0] = __builtin_amdgcn_mfma_f32_16x16x32_bf16(a2, breg0[ks], acc[2][0], 0, 0, 0);
                    acc[2][1] = __builtin_amdgcn_mfma_f32_16x16x32_bf16(a2, breg1[ks], acc[2][1], 0, 0, 0);
                    acc[3][0] = __builtin_amdgcn_mfma_f32_16x16x32_bf16(a3, breg0[ks], acc[3][0], 0, 0, 0);
                    acc[3][1] = __builtin_amdgcn_mfma_f32_16x16x32_bf16(a3, breg1[ks], acc[3][1], 0, 0, 0);
                }
            }
        }

        // bar: kloop A-reads done; winv published
        asm volatile("s_waitcnt lgkmcnt(0)" ::: "memory");
        __builtin_amdgcn_s_barrier();
        asm volatile("" ::: "memory");

        // epilogue(tile): stg transpose + PE-table + f32x4 coalesced stores
        {
            float* stg = s_stg[wid];
            #pragma unroll
            for (int m = 0; m < 4; ++m) {
                asm volatile("s_waitcnt lgkmcnt(0)" ::: "memory");  // WAR on stg
                #pragma unroll
                for (int n = 0; n < 2; ++n)
                    #pragma unroll
                    for (int r = 0; r < 4; ++r)
                        stg[(lg * 4 + r) * STG + n * 16 + l15] = acc[m][n][r];
                asm volatile("s_waitcnt lgkmcnt(0)" ::: "memory");
                const int rl = lane >> 3;        // 0..7
                #pragma unroll
                for (int h = 0; h < 2; ++h) {
                    const int rr = rl + 8 * h;                 // 0..15
                    const int tr = m * 16 + rr;                // row in tile 0..63
                    f32x4 v = *(const f32x4*)(stg + rr * STG + 4 * q8);
                    const float iv = s_winv[tr];
                    f32x4 p = *(const f32x4*)(pe + (size_t)(t0 + tr) * D_FIX + dq);
                    v[0] = v[0] * iv + p[0];
                    v[1] = v[1] * iv + p[1];
                    v[2] = v[2] * iv + p[2];
                    v[3] = v[3] * iv + p[3];
                    *(f32x4*)(out + ((size_t)b * T + t0 + tr) * D_FIX + dq) = v;
                }
            }
        }

        // exp(tile+1) overwrites s_A (A-reads drained at the bar above)
        if (tile + 1 < NTILE) {
            exp_tile(t0 + BM);
            asm volatile("s_waitcnt lgkmcnt(0)" ::: "memory");
            __builtin_amdgcn_s_barrier();
            asm volatile("" ::: "memory");
        }
    }
}

// ---------------- fallback (round-1 f32 kernel) ----------------
#define FBM 32
#define BLOCK 256
__global__ __launch_bounds__(BLOCK) void gauss_up_f32(
    const float* __restrict__ enc, const float* __restrict__ dur,
    const float* __restrict__ rng, float* __restrict__ out,
    int T, int D, int ntiles)
{
    __shared__ float s_w[FBM][S_FIX];
    __shared__ float s_c[S_FIX];
    __shared__ float s_ir2[S_FIX];
    __shared__ float s_scan[S_FIX];
    __shared__ float s_part[8][FBM];
    __shared__ float s_winv[FBM];

    const int tid = threadIdx.x;
    const int b   = blockIdx.x / ntiles;
    const int t0  = (blockIdx.x % ntiles) * FBM;

    float dv = dur[b * S_FIX + tid];
    s_scan[tid] = dv;
    __syncthreads();
    #pragma unroll
    for (int off = 1; off < S_FIX; off <<= 1) {
        float cur = s_scan[tid];
        float add = (tid >= off) ? s_scan[tid - off] : 0.0f;
        __syncthreads();
        s_scan[tid] = cur + add;
        __syncthreads();
    }
    {
        float e = s_scan[tid];
        float c = e - 0.5f * dv;
        float r = rng[b * S_FIX + tid];
        s_c[tid] = c; s_ir2[tid] = 1.0f / (r * r);
    }
    __syncthreads();
    {
        float cc = s_c[tid], ir = s_ir2[tid];
        #pragma unroll 4
        for (int tl = 0; tl < FBM; ++tl) {
            float tt = (float)(t0 + tl);
            float df = tt - cc;
            s_w[tl][tid] = __expf(-ir * df * df);
        }
    }
    __syncthreads();
    {
        const int t = tid & 31, ch = tid >> 5;
        float ps = 0.0f;
        #pragma unroll 8
        for (int j = 0; j < 32; ++j) ps += s_w[t][ch * 32 + ((j + t) & 31)];
        s_part[ch][t] = ps;
    }
    __syncthreads();
    if (tid < FBM) {
        float w2 = s_part[0][tid] + s_part[1][tid] + s_part[2][tid] + s_part[3][tid]
                 + s_part[4][tid] + s_part[5][tid] + s_part[6][tid] + s_part[7][tid] + 1e-20f;
        s_winv[tid] = 1.0f / w2;
    }
    __syncthreads();

    const int dq = tid & 63, tg = tid >> 6;
    float4 acc[8];
    #pragma unroll
    for (int i = 0; i < 8; ++i) acc[i] = make_float4(0.f, 0.f, 0.f, 0.f);
    const float* encb = enc + (size_t)b * S_FIX * D + (size_t)dq * 4;
    #pragma unroll 4
    for (int s = 0; s < S_FIX; ++s) {
        float4 ev = *(const float4*)(encb + (size_t)s * D);
        #pragma unroll
        for (int i = 0; i < 8; ++i) {
            float wv = s_w[tg * 8 + i][s];
            acc[i].x = fmaf(wv, ev.x, acc[i].x);
            acc[i].y = fmaf(wv, ev.y, acc[i].y);
            acc[i].z = fmaf(wv, ev.z, acc[i].z);
            acc[i].w = fmaf(wv, ev.w, acc[i].w);
        }
    }
    const float kf = -logf(10000.0f) / (float)D;
    const int d0 = dq * 4;
    const float f0 = __expf(kf * (float)(d0));
    const float f2 = __expf(kf * (float)(d0 + 2));
    float* outb = out + (size_t)b * T * D + (size_t)t0 * D + d0;
    #pragma unroll
    for (int i = 0; i < 8; ++i) {
        const int tl = tg * 8 + i;
        const float inv = s_winv[tl];
        const float tt = (float)(t0 + tl);
        const float a0 = tt * f0, a2 = tt * f2;
        float4 o;
        o.x = acc[i].x * inv + __sinf(a0);
        o.y = acc[i].y * inv + __cosf(a0);
        o.z = acc[i].z * inv + __sinf(a2);
        o.w = acc[i].w * inv + __cosf(a2);
        *(float4*)(outb + (size_t)tl * D) = o;
    }
}

extern "C" void kernel_launch(void* const* d_in, const int* in_sizes, int n_in,
                              void* d_out, int out_size, void* d_ws, size_t ws_size,
                              hipStream_t stream) {
    const float* enc = (const float*)d_in[0];
    const float* dur = (const float*)d_in[1];
    const float* rng = (const float*)d_in[2];
    float* out = (float*)d_out;

    const int S  = S_FIX;
    const int BS = in_sizes[1];
    const int B  = BS / S;
    const int D  = in_sizes[0] / BS;
    const int T  = out_size / (B * D);

    const size_t sz_encT = (size_t)B * D * S * sizeof(unsigned short);  // 4 MB
    const size_t sz_pe   = (size_t)T * D * sizeof(float);               // 2 MB
    const size_t need    = sz_encT + sz_pe;

    if (D == D_FIX && S == S_FIX && (T % (BM * NTILE)) == 0 && ws_size >= need) {
        unsigned short* encT = (unsigned short*)d_ws;
        float* pe = (float*)((char*)d_ws + sz_encT);
        hipLaunchKernelGGL(transpose_enc_bf16, dim3(B * (S / 8) * D / 256), dim3(256),
                           0, stream, enc, encT);
        hipLaunchKernelGGL(pe_table, dim3(T * 64 / 256), dim3(256), 0, stream, pe);
        const int grid = B * (T / (BM * NTILE));   // 32*8 = 256
        hipLaunchKernelGGL(gauss_fused6, dim3(grid), dim3(512), 0, stream,
                           dur, rng, encT, pe, out, T);
    } else {
        const int ntiles = T / FBM;
        hipLaunchKernelGGL(gauss_up_f32, dim3(B * ntiles), dim3(BLOCK), 0, stream,
                           enc, dur, rng, out, T, D, ntiles);
    }
}